// Round 16
// baseline (193.428 us; speedup 1.0000x reference)
//
#include <hip/hip_runtime.h>
#include <hip/hip_bf16.h>

#define B_    2
#define NSEQ  2048
#define FDIM  1024
#define NH    16
#define HD    64
#define MTOT  (B_*NSEQ)   // 4096
#define BHSZ  (NSEQ*HD)   // 131072 elems per (b,h) for K/V frag buffers

typedef __bf16 bf16_t;
typedef __bf16 bf16x4 __attribute__((ext_vector_type(4)));
typedef __bf16 bf16x8 __attribute__((ext_vector_type(8)));
typedef float  f32x4  __attribute__((ext_vector_type(4)));

#define AS1 __attribute__((address_space(1)))
#define AS3 __attribute__((address_space(3)))

__device__ __forceinline__ void gld_lds16(const bf16_t* g, bf16_t* l) {
  __builtin_amdgcn_global_load_lds((const AS1 void*)g, (AS3 void*)l, 16, 0, 0);
}

// K=16 bf16 MFMA for PV (P^T C-layout reg r == B-operand k-index j).
__device__ __forceinline__ f32x4 mfma_pv(bf16x4 a, bf16x4 b, f32x4 c) {
#if defined(__HIP_DEVICE_COMPILE__)
#if __has_builtin(__builtin_amdgcn_mfma_f32_16x16x16bf16_1k)
  typedef short s4 __attribute__((ext_vector_type(4)));
  return __builtin_amdgcn_mfma_f32_16x16x16bf16_1k(
      __builtin_bit_cast(s4, a), __builtin_bit_cast(s4, b), c, 0, 0, 0);
#else
  asm("v_mfma_f32_16x16x16_bf16 %0, %1, %2, %0" : "+v"(c) : "v"(a), "v"(b));
  return c;
#endif
#else
  (void)a; (void)b;
  return c;
#endif
}

// ---------------------------------------------------------------------------
// Kernel 1: fp32 -> bf16 casts for x, Wq, Wk, Wv, Wo
// ---------------------------------------------------------------------------
extern "C" __global__ __launch_bounds__(256) void cast_all_k(
    const float* __restrict__ x,  const float* __restrict__ wq,
    const float* __restrict__ wk, const float* __restrict__ wv,
    const float* __restrict__ wo,
    bf16_t* __restrict__ xb,  bf16_t* __restrict__ wqb,
    bf16_t* __restrict__ wkb, bf16_t* __restrict__ wvb,
    bf16_t* __restrict__ wob)
{
  long t = (long)blockIdx.x * blockDim.x + threadIdx.x;
  long i = t * 4;
  const float* src; bf16_t* dst; long off;
  if      (i < 4194304L) { src = x;  dst = xb;  off = i; }
  else if (i < 5242880L) { src = wq; dst = wqb; off = i - 4194304L; }
  else if (i < 6291456L) { src = wk; dst = wkb; off = i - 5242880L; }
  else if (i < 7340032L) { src = wv; dst = wvb; off = i - 6291456L; }
  else                   { src = wo; dst = wob; off = i - 7340032L; }
  float4 v = *(const float4*)(src + off);
  bf16x4 o = { (bf16_t)v.x, (bf16_t)v.y, (bf16_t)v.z, (bf16_t)v.w };
  *(bf16x4*)(dst + off) = o;
}

// ---------------------------------------------------------------------------
// Kernel 2: QKV bf16 GEMM out[m][n] = sum_k A[m][k]*W[n][k], BK=128
// (4 k-sub-slabs of 32 per barrier: 8 K-iterations, 32 MFMA/wave per drain —
// halves total barrier-drains vs BK=64 at the same 128x128 tile).
// 512 thr / 8 waves (64x32 C-tile per wave). LDS 64 KB staging (2 blk/CU).
// mode 0: Q scaled 0.125 [b][h][tok][d]   mode 1: K frag-linear
// mode 2: V frag-linear
// ---------------------------------------------------------------------------
extern "C" __global__ __launch_bounds__(512) void gemm_bt_k(
    const bf16_t* __restrict__ A,
    const bf16_t* __restrict__ Bq, const bf16_t* __restrict__ Bk,
    const bf16_t* __restrict__ Bv,
    bf16_t* __restrict__ oq, bf16_t* __restrict__ okk,
    bf16_t* __restrict__ ovt)
{
  __shared__ __align__(16) char garena[65536];   // 64 KB staging / 33 KB Tl
  bf16_t* As = (bf16_t*)garena;                  // 16384 elems (32 KB), 4 subs
  bf16_t* Bs = (bf16_t*)(garena + 32768);        // 16384 elems (32 KB), 4 subs
  const int K = FDIM;
  int mode = blockIdx.z;
  const bf16_t* Bw = (mode == 0) ? Bq : (mode == 1) ? Bk : Bv;
  int m0 = blockIdx.y * 128, n0 = blockIdx.x * 128;
  int tid = threadIdx.x, lane = tid & 63, wave = tid >> 6;
  int g = lane >> 4, c = lane & 15;
  int wm = (wave & 1) * 64, wn = (wave >> 1) * 32;
  f32x4 acc[4][2];
  for (int i = 0; i < 4; ++i)
    for (int j = 0; j < 2; ++j)
      acc[i][j] = (f32x4){0.f, 0.f, 0.f, 0.f};

  int srow = lane >> 2;
  int scol = (lane & 3) * 8;

  for (int kt = 0; kt < K / 128; ++kt) {
    int kk = kt * 128;
    // stage BK=128 slab: 4 sub-slabs of 32k, chunk = wave (16 rows)
#pragma unroll
    for (int sub = 0; sub < 4; ++sub) {
      const bf16_t* ag = A  + (long)(m0 + wave*16 + srow) * K + kk + sub*32 + scol;
      const bf16_t* bg = Bw + (long)(n0 + wave*16 + srow) * K + kk + sub*32 + scol;
      gld_lds16(ag, As + sub*4096 + wave*512);
      gld_lds16(bg, Bs + sub*4096 + wave*512);
    }
    __syncthreads();
#pragma unroll
    for (int sub = 0; sub < 4; ++sub) {
      bf16x8 af[4], bfr[2];
      for (int t = 0; t < 4; ++t)
        af[t]  = *(const bf16x8*)(As + sub*4096 + (wm + t*16 + c) * 32 + g * 8);
      for (int t = 0; t < 2; ++t)
        bfr[t] = *(const bf16x8*)(Bs + sub*4096 + (wn + t*16 + c) * 32 + g * 8);
      for (int mt = 0; mt < 4; ++mt)
        for (int nt = 0; nt < 2; ++nt)
          acc[mt][nt] = __builtin_amdgcn_mfma_f32_16x16x32_bf16(
              af[mt], bfr[nt], acc[mt][nt], 0, 0, 0);
    }
    __syncthreads();
  }

  // ---- LDS-coalesced epilogue (Tl reuses staging arena) ----
  bf16_t* Tl = (bf16_t*)garena;   // 128 x 132 bf16 = 33792 B < 64 KB
  float sc = (mode == 0) ? 0.125f : 1.0f;
  if (mode < 2) {
    for (int mt = 0; mt < 4; ++mt)
      for (int nt = 0; nt < 2; ++nt) {
        int nloc = wn + nt*16 + c;
        for (int r = 0; r < 4; ++r) {
          int mloc = wm + mt*16 + g*4 + r;
          Tl[mloc*132 + nloc] = (bf16_t)(acc[mt][nt][r] * sc);
        }
      }
  } else {
    for (int mt = 0; mt < 4; ++mt)
      for (int nt = 0; nt < 2; ++nt) {
        int nloc = wn + nt*16 + c;
        int mloc = wm + mt*16 + g*4;
        bf16x4 pk = { (bf16_t)acc[mt][nt][0], (bf16_t)acc[mt][nt][1],
                      (bf16_t)acc[mt][nt][2], (bf16_t)acc[mt][nt][3] };
        *(bf16x4*)(Tl + nloc*132 + mloc) = pk;
      }
  }
  __syncthreads();

  int b = m0 >> 11, m0loc = m0 & 2047;
  int h0 = n0 >> 6, tile0 = m0loc >> 6;
#pragma unroll
  for (int u = 0; u < 4; ++u) {
    int chunk = u * 512 + tid;            // 2048 chunks of 8 elems
    bf16_t* dst;
    int sidx;
    if (mode == 0) {
      int headloc = chunk >> 10, o = chunk & 1023;
      int tokloc = o >> 3, dd = (o & 7) * 8;
      sidx = tokloc*132 + headloc*64 + dd;
      dst = oq + ((long)(b*NH + h0 + headloc) * NSEQ + m0loc) * HD + (long)o * 8;
    } else if (mode == 1) {
      int region = chunk >> 9, o = chunk & 511;
      int headloc = region >> 1, t = region & 1;
      int f = o >> 6, rest = o & 63;
      int mtA = f >> 1, kh = f & 1, gK = rest >> 4, cA = rest & 15;
      int tokloc = t*64 + mtA*16 + cA;
      sidx = tokloc*132 + headloc*64 + kh*32 + gK*8;
      dst = okk + (long)(b*NH + h0 + headloc) * BHSZ
            + (long)(tile0 + t) * 4096 + (long)o * 8;
    } else {
      int region = chunk >> 9, o = chunk & 511;
      int headloc = region >> 1, t = region & 1;
      int frag = o >> 5, so = o & 31;
      int mtA = frag >> 2, dtA = frag & 3;
      int slot0 = so * 2;
      int cA = slot0 >> 2, gA0 = slot0 & 3;
      int k0loc = t*64 + mtA*16 + gA0*4;
      int nloc = headloc*64 + dtA*16 + cA;
      sidx = nloc*132 + k0loc;
      dst = ovt + (long)(b*NH + h0 + headloc) * BHSZ
            + (long)(tile0 + t) * 4096 + (long)o * 8;
    }
    bf16x4 lo = *(const bf16x4*)(Tl + sidx);
    bf16x4 hi = *(const bf16x4*)(Tl + sidx + 4);
    bf16x8 v;
#pragma unroll
    for (int i = 0; i < 4; ++i) { v[i] = lo[i]; v[i+4] = hi[i]; }
    *(bf16x8*)dst = v;
  }
}

// ---------------------------------------------------------------------------
// Kernel 4: output GEMM out[m][n] = sum_k A[m][k]*Wo[n][k] + bias[n], fp32.
// 128x64 tile, BK=64, 512 thr / 8 waves (32x32 C-tile per wave) — round-15
// structure kept (measured insensitive to further TLP).
// ---------------------------------------------------------------------------
extern "C" __global__ __launch_bounds__(512) void gemm_out_k(
    const bf16_t* __restrict__ A, const bf16_t* __restrict__ W,
    const float* __restrict__ bias, float* __restrict__ out)
{
  __shared__ __align__(16) bf16_t As[8192];   // 128 rows x 64 k (16 KB)
  __shared__ __align__(16) bf16_t Bs[4096];   //  64 rows x 64 k ( 8 KB)
  const int K = FDIM;
  int m0 = blockIdx.y * 128, n0 = blockIdx.x * 64;
  int tid = threadIdx.x, lane = tid & 63, wave = tid >> 6;
  int g = lane >> 4, c = lane & 15;
  int wm = (wave & 3) * 32, wn = (wave >> 2) * 32;
  f32x4 acc[2][2];
  for (int i = 0; i < 2; ++i)
    for (int j = 0; j < 2; ++j)
      acc[i][j] = (f32x4){0.f, 0.f, 0.f, 0.f};

  int srow = lane >> 2;
  int scol = (lane & 3) * 8;

  for (int kt = 0; kt < K / 64; ++kt) {
    int kk = kt * 64;
    {
      const bf16_t* ag = A + (long)(m0 + wave*16 + srow) * K + kk + scol;
      gld_lds16(ag,      As + wave * 512);
      gld_lds16(ag + 32, As + 4096 + wave * 512);
      if (wave < 4) {
        const bf16_t* bg = W + (long)(n0 + wave*16 + srow) * K + kk + scol;
        gld_lds16(bg,      Bs + wave * 512);
        gld_lds16(bg + 32, Bs + 2048 + wave * 512);
      }
    }
    __syncthreads();
    bf16x8 af[2][2], bfr[2][2];
    for (int t = 0; t < 2; ++t) {
      af[t][0]  = *(const bf16x8*)(As + (wm + t*16 + c) * 32 + g * 8);
      af[t][1]  = *(const bf16x8*)(As + 4096 + (wm + t*16 + c) * 32 + g * 8);
      bfr[t][0] = *(const bf16x8*)(Bs + (wn + t*16 + c) * 32 + g * 8);
      bfr[t][1] = *(const bf16x8*)(Bs + 2048 + (wn + t*16 + c) * 32 + g * 8);
    }
    for (int mt = 0; mt < 2; ++mt)
      for (int nt = 0; nt < 2; ++nt) {
        acc[mt][nt] = __builtin_amdgcn_mfma_f32_16x16x32_bf16(
            af[mt][0], bfr[nt][0], acc[mt][nt], 0, 0, 0);
        acc[mt][nt] = __builtin_amdgcn_mfma_f32_16x16x32_bf16(
            af[mt][1], bfr[nt][1], acc[mt][nt], 0, 0, 0);
      }
    __syncthreads();
  }

  for (int mt = 0; mt < 2; ++mt)
    for (int nt = 0; nt < 2; ++nt) {
      int n = n0 + wn + nt*16 + c;
      float bv = bias[n];
      for (int r = 0; r < 4; ++r) {
        int m = m0 + wm + mt*16 + g*4 + r;
        out[(long)m * FDIM + n] = acc[mt][nt][r] + bv;
      }
    }
}

// ---------------------------------------------------------------------------
// Kernel 3: flash attention (round-13 structure verbatim — 59.4 us).
// Transposed-S, no-max softmax (__expf native), in-block key-split,
// LDS-staged K/V via global_load_lds from frag-linear layout,
// double-buffered per half.
// ---------------------------------------------------------------------------
extern "C" __global__ __launch_bounds__(512) void attn_fused_k(
    const bf16_t* __restrict__ q, const bf16_t* __restrict__ k,
    const bf16_t* __restrict__ vt, bf16_t* __restrict__ attn)
{
  __shared__ __align__(16) char arena[65536];
  __shared__ float Ll[128];
  int bh = blockIdx.y;
  int tid = threadIdx.x, lane = tid & 63, wave = tid >> 6;
  int g = lane >> 4, c = lane & 15;
  int qg = wave & 3, half = wave >> 2;
  int qw = blockIdx.x * 128 + qg * 32;
  const bf16_t* Q  = q  + (long)bh * NSEQ * HD;
  const bf16_t* Kf = k  + (long)bh * BHSZ;
  const bf16_t* Vf = vt + (long)bh * BHSZ;

  bf16x8 bQ[2][2];
#pragma unroll
  for (int s = 0; s < 2; ++s)
#pragma unroll
    for (int hh = 0; hh < 2; ++hh)
      bQ[s][hh] = *(const bf16x8*)(Q + (long)(qw + s*16 + c) * HD + hh*32 + g*8);

  f32x4 acc[2][4];
  f32x4 lsum[2];
#pragma unroll
  for (int s = 0; s < 2; ++s) {
#pragma unroll
    for (int dt = 0; dt < 4; ++dt) acc[s][dt] = (f32x4){0.f, 0.f, 0.f, 0.f};
    lsum[s] = (f32x4){0.f, 0.f, 0.f, 0.f};
  }

  int w4 = wave & 3, ln = lane;
  const int NT = NSEQ / 128;              // 16 tiles per half
  int kbase = half * (NSEQ / 2);

  auto stage = [&](int buf, int k0) {
    bf16_t* Kb = (bf16_t*)(arena + buf * 32768 + half * 16384);
    bf16_t* Vb = Kb + 4096;
    long tbase = (long)(k0 >> 6) * 4096;
#pragma unroll
    for (int j = 0; j < 2; ++j) {
      int ch = j*4 + w4;
      gld_lds16(Kf + tbase + ch*512 + ln*8, Kb + ch*512);
      gld_lds16(Vf + tbase + ch*512 + ln*8, Vb + ch*512);
    }
  };

  stage(0, kbase);
  __syncthreads();

  for (int kt = 0; kt < NT; ++kt) {
    int cur = kt & 1;
    if (kt + 1 < NT) stage(cur ^ 1, kbase + (kt + 1) * 64);

    const bf16_t* Kb = (const bf16_t*)(arena + cur * 32768 + half * 16384);
    const bf16_t* Vb = Kb + 4096;

    f32x4 St[2][4];
#pragma unroll
    for (int mt = 0; mt < 4; ++mt) {
      bf16x8 k0f = *(const bf16x8*)(Kb + (mt*2 + 0) * 512 + lane * 8);
      bf16x8 k1f = *(const bf16x8*)(Kb + (mt*2 + 1) * 512 + lane * 8);
#pragma unroll
      for (int s = 0; s < 2; ++s) {
        f32x4 z = (f32x4){0.f, 0.f, 0.f, 0.f};
        z = __builtin_amdgcn_mfma_f32_16x16x32_bf16(k0f, bQ[s][0], z, 0, 0, 0);
        z = __builtin_amdgcn_mfma_f32_16x16x32_bf16(k1f, bQ[s][1], z, 0, 0, 0);
        St[s][mt] = z;
      }
    }

    bf16x4 bP[2][4];
#pragma unroll
    for (int s = 0; s < 2; ++s)
#pragma unroll
      for (int mt = 0; mt < 4; ++mt) {
#pragma unroll
        for (int r = 0; r < 4; ++r) {
          float p = __expf(St[s][mt][r]);
          St[s][mt][r] = p;
          lsum[s][r] += p;
        }
        bP[s][mt] = (bf16x4){(bf16_t)St[s][mt][0], (bf16_t)St[s][mt][1],
                             (bf16_t)St[s][mt][2], (bf16_t)St[s][mt][3]};
      }

#pragma unroll
    for (int mt = 0; mt < 4; ++mt)
#pragma unroll
      for (int dt = 0; dt < 4; ++dt) {
        bf16x4 aV = *(const bf16x4*)(Vb + (mt*4 + dt) * 256 + (c*4 + g) * 4);
        acc[0][dt] = mfma_pv(aV, bP[0][mt], acc[0][dt]);
        acc[1][dt] = mfma_pv(aV, bP[1][mt], acc[1][dt]);
      }

    __syncthreads();
  }

  float lp[2];
#pragma unroll
  for (int s = 0; s < 2; ++s) {
    float p = (lsum[s][0] + lsum[s][1]) + (lsum[s][2] + lsum[s][3]);
    p += __shfl_xor(p, 16);
    p += __shfl_xor(p, 32);
    lp[s] = p;
  }

  float* Opart = (float*)arena;                       // 128 x 72 f32 = 36 KB
  bf16_t* Tb = (bf16_t*)(arena + 36864);              // 128 x 80 bf16 = 20 KB
  if (half == 1) {
#pragma unroll
    for (int s = 0; s < 2; ++s) {
      int qrow = qg*32 + s*16 + c;
#pragma unroll
      for (int dt = 0; dt < 4; ++dt)
        *(f32x4*)(Opart + qrow*72 + dt*16 + g*4) = acc[s][dt];
      if (g == 0) Ll[qrow] = lp[s];
    }
  }
  __syncthreads();
  if (half == 0) {
#pragma unroll
    for (int s = 0; s < 2; ++s) {
      int qrow = qg*32 + s*16 + c;
      float inv = 1.f / (lp[s] + Ll[qrow]);
#pragma unroll
      for (int dt = 0; dt < 4; ++dt) {
        f32x4 part = *(const f32x4*)(Opart + qrow*72 + dt*16 + g*4);
#pragma unroll
        for (int r = 0; r < 4; ++r)
          Tb[qrow*80 + dt*16 + g*4 + r] =
              (bf16_t)((acc[s][dt][r] + part[r]) * inv);
      }
    }
  }
  __syncthreads();
  int b = bh >> 4, h = bh & 15;
  int row = tid >> 2, dseg = (tid & 3) * 16;
  const bf16_t* src = Tb + row*80 + dseg;
  bf16_t* dst = attn + ((long)(b * NSEQ + blockIdx.x*128 + row)) * FDIM + h * HD + dseg;
  *(bf16x8*)(dst)     = *(const bf16x8*)(src);
  *(bf16x8*)(dst + 8) = *(const bf16x8*)(src + 8);
}

// ---------------------------------------------------------------------------
extern "C" void kernel_launch(void* const* d_in, const int* in_sizes, int n_in,
                              void* d_out, int out_size, void* d_ws, size_t ws_size,
                              hipStream_t stream)
{
  const float* x  = (const float*)d_in[0];
  const float* wq = (const float*)d_in[1];
  const float* wk = (const float*)d_in[2];
  const float* wv = (const float*)d_in[3];
  const float* wo = (const float*)d_in[4];
  const float* bo = (const float*)d_in[5];
  float* out = (float*)d_out;
  char* ws = (char*)d_ws;

  const size_t MB = 1024 * 1024;
  bf16_t* xb    = (bf16_t*)(ws);
  bf16_t* wqb   = (bf16_t*)(ws + 8  * MB);
  bf16_t* wkb   = (bf16_t*)(ws + 10 * MB);
  bf16_t* wvb   = (bf16_t*)(ws + 12 * MB);
  bf16_t* wob   = (bf16_t*)(ws + 14 * MB);
  bf16_t* q_ws  = (bf16_t*)(ws + 16 * MB);
  bf16_t* k_ws  = (bf16_t*)(ws + 24 * MB);   // frag-linear per (b,h)
  bf16_t* vt_ws = (bf16_t*)(ws + 32 * MB);   // frag-linear per (b,h)
  bf16_t* at_ws = (bf16_t*)(ws + 40 * MB);

  hipLaunchKernelGGL(cast_all_k, dim3(8192), dim3(256), 0, stream,
                     x, wq, wk, wv, wo, xb, wqb, wkb, wvb, wob);

  hipLaunchKernelGGL(gemm_bt_k, dim3(8, 32, 3), dim3(512), 0, stream,
                     xb, wqb, wkb, wvb, q_ws, k_ws, vt_ws);

  hipLaunchKernelGGL(attn_fused_k, dim3(16, 32), dim3(512), 0, stream,
                     q_ws, k_ws, vt_ws, at_ws);

  hipLaunchKernelGGL(gemm_out_k, dim3(16, 32), dim3(512), 0, stream,
                     at_ws, wob, bo, out);
}

// Round 17
// 185.752 us; speedup vs baseline: 1.0413x; 1.0413x over previous
//
#include <hip/hip_runtime.h>
#include <hip/hip_bf16.h>

#define B_    2
#define NSEQ  2048
#define FDIM  1024
#define NH    16
#define HD    64
#define MTOT  (B_*NSEQ)   // 4096
#define BHSZ  (NSEQ*HD)   // 131072 elems per (b,h) for K/V frag buffers

typedef __bf16 bf16_t;
typedef __bf16 bf16x4 __attribute__((ext_vector_type(4)));
typedef __bf16 bf16x8 __attribute__((ext_vector_type(8)));
typedef float  f32x4  __attribute__((ext_vector_type(4)));

#define AS1 __attribute__((address_space(1)))
#define AS3 __attribute__((address_space(3)))

__device__ __forceinline__ void gld_lds16(const bf16_t* g, bf16_t* l) {
  __builtin_amdgcn_global_load_lds((const AS1 void*)g, (AS3 void*)l, 16, 0, 0);
}

// K=16 bf16 MFMA for PV (P^T C-layout reg r == B-operand k-index j).
__device__ __forceinline__ f32x4 mfma_pv(bf16x4 a, bf16x4 b, f32x4 c) {
#if defined(__HIP_DEVICE_COMPILE__)
#if __has_builtin(__builtin_amdgcn_mfma_f32_16x16x16bf16_1k)
  typedef short s4 __attribute__((ext_vector_type(4)));
  return __builtin_amdgcn_mfma_f32_16x16x16bf16_1k(
      __builtin_bit_cast(s4, a), __builtin_bit_cast(s4, b), c, 0, 0, 0);
#else
  asm("v_mfma_f32_16x16x16_bf16 %0, %1, %2, %0" : "+v"(c) : "v"(a), "v"(b));
  return c;
#endif
#else
  (void)a; (void)b;
  return c;
#endif
}

// ---------------------------------------------------------------------------
// Kernel 1: fp32 -> bf16 casts for x, Wq, Wk, Wv, Wo
// ---------------------------------------------------------------------------
extern "C" __global__ __launch_bounds__(256) void cast_all_k(
    const float* __restrict__ x,  const float* __restrict__ wq,
    const float* __restrict__ wk, const float* __restrict__ wv,
    const float* __restrict__ wo,
    bf16_t* __restrict__ xb,  bf16_t* __restrict__ wqb,
    bf16_t* __restrict__ wkb, bf16_t* __restrict__ wvb,
    bf16_t* __restrict__ wob)
{
  long t = (long)blockIdx.x * blockDim.x + threadIdx.x;
  long i = t * 4;
  const float* src; bf16_t* dst; long off;
  if      (i < 4194304L) { src = x;  dst = xb;  off = i; }
  else if (i < 5242880L) { src = wq; dst = wqb; off = i - 4194304L; }
  else if (i < 6291456L) { src = wk; dst = wkb; off = i - 5242880L; }
  else if (i < 7340032L) { src = wv; dst = wvb; off = i - 6291456L; }
  else                   { src = wo; dst = wob; off = i - 7340032L; }
  float4 v = *(const float4*)(src + off);
  bf16x4 o = { (bf16_t)v.x, (bf16_t)v.y, (bf16_t)v.z, (bf16_t)v.w };
  *(bf16x4*)(dst + off) = o;
}

// ---------------------------------------------------------------------------
// Kernel 2: QKV bf16 GEMM out[m][n] = sum_k A[m][k]*W[n][k], BK=64,
// 128x128 tile, 512 thr / 8 waves (64x32 C-tile per wave).
// GRID AXES SWAPPED for XCD L2 locality: blockIdx.x = m-tile (A-row-slab
// sharers land id-stride-32 == same XCD -> A fetched into ONE L2, not 8);
// weight-slab sharers become stride-1 (weights are 6 MB total, cheap).
// mode 0: Q scaled 0.125 [b][h][tok][d]   mode 1: K frag-linear
// mode 2: V frag-linear
// ---------------------------------------------------------------------------
extern "C" __global__ __launch_bounds__(512) void gemm_bt_k(
    const bf16_t* __restrict__ A,
    const bf16_t* __restrict__ Bq, const bf16_t* __restrict__ Bk,
    const bf16_t* __restrict__ Bv,
    bf16_t* __restrict__ oq, bf16_t* __restrict__ okk,
    bf16_t* __restrict__ ovt)
{
  __shared__ __align__(16) char garena[33792];   // 32 KB staging / 33 KB Tl
  bf16_t* As = (bf16_t*)garena;                  // 8192 elems (16 KB)
  bf16_t* Bs = (bf16_t*)(garena + 16384);        // 8192 elems (16 KB)
  const int K = FDIM;
  int mode = blockIdx.z;
  const bf16_t* Bw = (mode == 0) ? Bq : (mode == 1) ? Bk : Bv;
  int m0 = blockIdx.x * 128, n0 = blockIdx.y * 128;   // axes swapped
  int tid = threadIdx.x, lane = tid & 63, wave = tid >> 6;
  int g = lane >> 4, c = lane & 15;
  int wm = (wave & 1) * 64, wn = (wave >> 1) * 32;
  f32x4 acc[4][2];
  for (int i = 0; i < 4; ++i)
    for (int j = 0; j < 2; ++j)
      acc[i][j] = (f32x4){0.f, 0.f, 0.f, 0.f};

  int srow = lane >> 2;
  int scol = (lane & 3) * 8;

  for (int kt = 0; kt < K / 64; ++kt) {
    int kk = kt * 64;
    {
      int chunk = wave;                     // 0..7, 16 rows each
      const bf16_t* ag = A  + (long)(m0 + chunk*16 + srow) * K + kk + scol;
      const bf16_t* bg = Bw + (long)(n0 + chunk*16 + srow) * K + kk + scol;
      gld_lds16(ag,      As + chunk * 512);
      gld_lds16(ag + 32, As + 4096 + chunk * 512);
      gld_lds16(bg,      Bs + chunk * 512);
      gld_lds16(bg + 32, Bs + 4096 + chunk * 512);
    }
    __syncthreads();
    bf16x8 af[4][2], bfr[2][2];
    for (int t = 0; t < 4; ++t) {
      af[t][0]  = *(const bf16x8*)(As + (wm + t*16 + c) * 32 + g * 8);
      af[t][1]  = *(const bf16x8*)(As + 4096 + (wm + t*16 + c) * 32 + g * 8);
    }
    for (int t = 0; t < 2; ++t) {
      bfr[t][0] = *(const bf16x8*)(Bs + (wn + t*16 + c) * 32 + g * 8);
      bfr[t][1] = *(const bf16x8*)(Bs + 4096 + (wn + t*16 + c) * 32 + g * 8);
    }
    for (int mt = 0; mt < 4; ++mt)
      for (int nt = 0; nt < 2; ++nt) {
        acc[mt][nt] = __builtin_amdgcn_mfma_f32_16x16x32_bf16(
            af[mt][0], bfr[nt][0], acc[mt][nt], 0, 0, 0);
        acc[mt][nt] = __builtin_amdgcn_mfma_f32_16x16x32_bf16(
            af[mt][1], bfr[nt][1], acc[mt][nt], 0, 0, 0);
      }
    __syncthreads();
  }

  // ---- LDS-coalesced epilogue ----
  bf16_t* Tl = (bf16_t*)garena;   // 128 x 132 bf16 = 33792 B
  float sc = (mode == 0) ? 0.125f : 1.0f;
  if (mode < 2) {
    for (int mt = 0; mt < 4; ++mt)
      for (int nt = 0; nt < 2; ++nt) {
        int nloc = wn + nt*16 + c;
        for (int r = 0; r < 4; ++r) {
          int mloc = wm + mt*16 + g*4 + r;
          Tl[mloc*132 + nloc] = (bf16_t)(acc[mt][nt][r] * sc);
        }
      }
  } else {
    for (int mt = 0; mt < 4; ++mt)
      for (int nt = 0; nt < 2; ++nt) {
        int nloc = wn + nt*16 + c;
        int mloc = wm + mt*16 + g*4;
        bf16x4 pk = { (bf16_t)acc[mt][nt][0], (bf16_t)acc[mt][nt][1],
                      (bf16_t)acc[mt][nt][2], (bf16_t)acc[mt][nt][3] };
        *(bf16x4*)(Tl + nloc*132 + mloc) = pk;
      }
  }
  __syncthreads();

  int b = m0 >> 11, m0loc = m0 & 2047;
  int h0 = n0 >> 6, tile0 = m0loc >> 6;
#pragma unroll
  for (int u = 0; u < 4; ++u) {
    int chunk = u * 512 + tid;            // 2048 chunks of 8 elems
    bf16_t* dst;
    int sidx;
    if (mode == 0) {
      int headloc = chunk >> 10, o = chunk & 1023;
      int tokloc = o >> 3, dd = (o & 7) * 8;
      sidx = tokloc*132 + headloc*64 + dd;
      dst = oq + ((long)(b*NH + h0 + headloc) * NSEQ + m0loc) * HD + (long)o * 8;
    } else if (mode == 1) {
      int region = chunk >> 9, o = chunk & 511;
      int headloc = region >> 1, t = region & 1;
      int f = o >> 6, rest = o & 63;
      int mtA = f >> 1, kh = f & 1, gK = rest >> 4, cA = rest & 15;
      int tokloc = t*64 + mtA*16 + cA;
      sidx = tokloc*132 + headloc*64 + kh*32 + gK*8;
      dst = okk + (long)(b*NH + h0 + headloc) * BHSZ
            + (long)(tile0 + t) * 4096 + (long)o * 8;
    } else {
      int region = chunk >> 9, o = chunk & 511;
      int headloc = region >> 1, t = region & 1;
      int frag = o >> 5, so = o & 31;
      int mtA = frag >> 2, dtA = frag & 3;
      int slot0 = so * 2;
      int cA = slot0 >> 2, gA0 = slot0 & 3;
      int k0loc = t*64 + mtA*16 + gA0*4;
      int nloc = headloc*64 + dtA*16 + cA;
      sidx = nloc*132 + k0loc;
      dst = ovt + (long)(b*NH + h0 + headloc) * BHSZ
            + (long)(tile0 + t) * 4096 + (long)o * 8;
    }
    bf16x4 lo = *(const bf16x4*)(Tl + sidx);
    bf16x4 hi = *(const bf16x4*)(Tl + sidx + 4);
    bf16x8 v;
#pragma unroll
    for (int i = 0; i < 4; ++i) { v[i] = lo[i]; v[i+4] = hi[i]; }
    *(bf16x8*)dst = v;
  }
}

// ---------------------------------------------------------------------------
// Kernel 4: output GEMM out[m][n] = sum_k A[m][k]*Wo[n][k] + bias[n], fp32.
// 128x64 tile, BK=64, 512 thr / 8 waves (32x32 C-tile per wave).
// GRID AXES SWAPPED: blockIdx.x = m-tile (A-sharers -> same XCD).
// ---------------------------------------------------------------------------
extern "C" __global__ __launch_bounds__(512) void gemm_out_k(
    const bf16_t* __restrict__ A, const bf16_t* __restrict__ W,
    const float* __restrict__ bias, float* __restrict__ out)
{
  __shared__ __align__(16) bf16_t As[8192];   // 128 rows x 64 k (16 KB)
  __shared__ __align__(16) bf16_t Bs[4096];   //  64 rows x 64 k ( 8 KB)
  const int K = FDIM;
  int m0 = blockIdx.x * 128, n0 = blockIdx.y * 64;    // axes swapped
  int tid = threadIdx.x, lane = tid & 63, wave = tid >> 6;
  int g = lane >> 4, c = lane & 15;
  int wm = (wave & 3) * 32, wn = (wave >> 2) * 32;
  f32x4 acc[2][2];
  for (int i = 0; i < 2; ++i)
    for (int j = 0; j < 2; ++j)
      acc[i][j] = (f32x4){0.f, 0.f, 0.f, 0.f};

  int srow = lane >> 2;
  int scol = (lane & 3) * 8;

  for (int kt = 0; kt < K / 64; ++kt) {
    int kk = kt * 64;
    {
      const bf16_t* ag = A + (long)(m0 + wave*16 + srow) * K + kk + scol;
      gld_lds16(ag,      As + wave * 512);
      gld_lds16(ag + 32, As + 4096 + wave * 512);
      if (wave < 4) {
        const bf16_t* bg = W + (long)(n0 + wave*16 + srow) * K + kk + scol;
        gld_lds16(bg,      Bs + wave * 512);
        gld_lds16(bg + 32, Bs + 2048 + wave * 512);
      }
    }
    __syncthreads();
    bf16x8 af[2][2], bfr[2][2];
    for (int t = 0; t < 2; ++t) {
      af[t][0]  = *(const bf16x8*)(As + (wm + t*16 + c) * 32 + g * 8);
      af[t][1]  = *(const bf16x8*)(As + 4096 + (wm + t*16 + c) * 32 + g * 8);
      bfr[t][0] = *(const bf16x8*)(Bs + (wn + t*16 + c) * 32 + g * 8);
      bfr[t][1] = *(const bf16x8*)(Bs + 2048 + (wn + t*16 + c) * 32 + g * 8);
    }
    for (int mt = 0; mt < 2; ++mt)
      for (int nt = 0; nt < 2; ++nt) {
        acc[mt][nt] = __builtin_amdgcn_mfma_f32_16x16x32_bf16(
            af[mt][0], bfr[nt][0], acc[mt][nt], 0, 0, 0);
        acc[mt][nt] = __builtin_amdgcn_mfma_f32_16x16x32_bf16(
            af[mt][1], bfr[nt][1], acc[mt][nt], 0, 0, 0);
      }
    __syncthreads();
  }

  for (int mt = 0; mt < 2; ++mt)
    for (int nt = 0; nt < 2; ++nt) {
      int n = n0 + wn + nt*16 + c;
      float bv = bias[n];
      for (int r = 0; r < 4; ++r) {
        int m = m0 + wm + mt*16 + g*4 + r;
        out[(long)m * FDIM + n] = acc[mt][nt][r] + bv;
      }
    }
}

// ---------------------------------------------------------------------------
// Kernel 3: flash attention (round-13 structure verbatim — 59.4 us).
// Transposed-S, no-max softmax (__expf native), in-block key-split,
// LDS-staged K/V via global_load_lds from frag-linear layout,
// double-buffered per half.
// ---------------------------------------------------------------------------
extern "C" __global__ __launch_bounds__(512) void attn_fused_k(
    const bf16_t* __restrict__ q, const bf16_t* __restrict__ k,
    const bf16_t* __restrict__ vt, bf16_t* __restrict__ attn)
{
  __shared__ __align__(16) char arena[65536];
  __shared__ float Ll[128];
  int bh = blockIdx.y;
  int tid = threadIdx.x, lane = tid & 63, wave = tid >> 6;
  int g = lane >> 4, c = lane & 15;
  int qg = wave & 3, half = wave >> 2;
  int qw = blockIdx.x * 128 + qg * 32;
  const bf16_t* Q  = q  + (long)bh * NSEQ * HD;
  const bf16_t* Kf = k  + (long)bh * BHSZ;
  const bf16_t* Vf = vt + (long)bh * BHSZ;

  bf16x8 bQ[2][2];
#pragma unroll
  for (int s = 0; s < 2; ++s)
#pragma unroll
    for (int hh = 0; hh < 2; ++hh)
      bQ[s][hh] = *(const bf16x8*)(Q + (long)(qw + s*16 + c) * HD + hh*32 + g*8);

  f32x4 acc[2][4];
  f32x4 lsum[2];
#pragma unroll
  for (int s = 0; s < 2; ++s) {
#pragma unroll
    for (int dt = 0; dt < 4; ++dt) acc[s][dt] = (f32x4){0.f, 0.f, 0.f, 0.f};
    lsum[s] = (f32x4){0.f, 0.f, 0.f, 0.f};
  }

  int w4 = wave & 3, ln = lane;
  const int NT = NSEQ / 128;              // 16 tiles per half
  int kbase = half * (NSEQ / 2);

  auto stage = [&](int buf, int k0) {
    bf16_t* Kb = (bf16_t*)(arena + buf * 32768 + half * 16384);
    bf16_t* Vb = Kb + 4096;
    long tbase = (long)(k0 >> 6) * 4096;
#pragma unroll
    for (int j = 0; j < 2; ++j) {
      int ch = j*4 + w4;
      gld_lds16(Kf + tbase + ch*512 + ln*8, Kb + ch*512);
      gld_lds16(Vf + tbase + ch*512 + ln*8, Vb + ch*512);
    }
  };

  stage(0, kbase);
  __syncthreads();

  for (int kt = 0; kt < NT; ++kt) {
    int cur = kt & 1;
    if (kt + 1 < NT) stage(cur ^ 1, kbase + (kt + 1) * 64);

    const bf16_t* Kb = (const bf16_t*)(arena + cur * 32768 + half * 16384);
    const bf16_t* Vb = Kb + 4096;

    f32x4 St[2][4];
#pragma unroll
    for (int mt = 0; mt < 4; ++mt) {
      bf16x8 k0f = *(const bf16x8*)(Kb + (mt*2 + 0) * 512 + lane * 8);
      bf16x8 k1f = *(const bf16x8*)(Kb + (mt*2 + 1) * 512 + lane * 8);
#pragma unroll
      for (int s = 0; s < 2; ++s) {
        f32x4 z = (f32x4){0.f, 0.f, 0.f, 0.f};
        z = __builtin_amdgcn_mfma_f32_16x16x32_bf16(k0f, bQ[s][0], z, 0, 0, 0);
        z = __builtin_amdgcn_mfma_f32_16x16x32_bf16(k1f, bQ[s][1], z, 0, 0, 0);
        St[s][mt] = z;
      }
    }

    bf16x4 bP[2][4];
#pragma unroll
    for (int s = 0; s < 2; ++s)
#pragma unroll
      for (int mt = 0; mt < 4; ++mt) {
#pragma unroll
        for (int r = 0; r < 4; ++r) {
          float p = __expf(St[s][mt][r]);
          St[s][mt][r] = p;
          lsum[s][r] += p;
        }
        bP[s][mt] = (bf16x4){(bf16_t)St[s][mt][0], (bf16_t)St[s][mt][1],
                             (bf16_t)St[s][mt][2], (bf16_t)St[s][mt][3]};
      }

#pragma unroll
    for (int mt = 0; mt < 4; ++mt)
#pragma unroll
      for (int dt = 0; dt < 4; ++dt) {
        bf16x4 aV = *(const bf16x4*)(Vb + (mt*4 + dt) * 256 + (c*4 + g) * 4);
        acc[0][dt] = mfma_pv(aV, bP[0][mt], acc[0][dt]);
        acc[1][dt] = mfma_pv(aV, bP[1][mt], acc[1][dt]);
      }

    __syncthreads();
  }

  float lp[2];
#pragma unroll
  for (int s = 0; s < 2; ++s) {
    float p = (lsum[s][0] + lsum[s][1]) + (lsum[s][2] + lsum[s][3]);
    p += __shfl_xor(p, 16);
    p += __shfl_xor(p, 32);
    lp[s] = p;
  }

  float* Opart = (float*)arena;                       // 128 x 72 f32 = 36 KB
  bf16_t* Tb = (bf16_t*)(arena + 36864);              // 128 x 80 bf16 = 20 KB
  if (half == 1) {
#pragma unroll
    for (int s = 0; s < 2; ++s) {
      int qrow = qg*32 + s*16 + c;
#pragma unroll
      for (int dt = 0; dt < 4; ++dt)
        *(f32x4*)(Opart + qrow*72 + dt*16 + g*4) = acc[s][dt];
      if (g == 0) Ll[qrow] = lp[s];
    }
  }
  __syncthreads();
  if (half == 0) {
#pragma unroll
    for (int s = 0; s < 2; ++s) {
      int qrow = qg*32 + s*16 + c;
      float inv = 1.f / (lp[s] + Ll[qrow]);
#pragma unroll
      for (int dt = 0; dt < 4; ++dt) {
        f32x4 part = *(const f32x4*)(Opart + qrow*72 + dt*16 + g*4);
#pragma unroll
        for (int r = 0; r < 4; ++r)
          Tb[qrow*80 + dt*16 + g*4 + r] =
              (bf16_t)((acc[s][dt][r] + part[r]) * inv);
      }
    }
  }
  __syncthreads();
  int b = bh >> 4, h = bh & 15;
  int row = tid >> 2, dseg = (tid & 3) * 16;
  const bf16_t* src = Tb + row*80 + dseg;
  bf16_t* dst = attn + ((long)(b * NSEQ + blockIdx.x*128 + row)) * FDIM + h * HD + dseg;
  *(bf16x8*)(dst)     = *(const bf16x8*)(src);
  *(bf16x8*)(dst + 8) = *(const bf16x8*)(src + 8);
}

// ---------------------------------------------------------------------------
extern "C" void kernel_launch(void* const* d_in, const int* in_sizes, int n_in,
                              void* d_out, int out_size, void* d_ws, size_t ws_size,
                              hipStream_t stream)
{
  const float* x  = (const float*)d_in[0];
  const float* wq = (const float*)d_in[1];
  const float* wk = (const float*)d_in[2];
  const float* wv = (const float*)d_in[3];
  const float* wo = (const float*)d_in[4];
  const float* bo = (const float*)d_in[5];
  float* out = (float*)d_out;
  char* ws = (char*)d_ws;

  const size_t MB = 1024 * 1024;
  bf16_t* xb    = (bf16_t*)(ws);
  bf16_t* wqb   = (bf16_t*)(ws + 8  * MB);
  bf16_t* wkb   = (bf16_t*)(ws + 10 * MB);
  bf16_t* wvb   = (bf16_t*)(ws + 12 * MB);
  bf16_t* wob   = (bf16_t*)(ws + 14 * MB);
  bf16_t* q_ws  = (bf16_t*)(ws + 16 * MB);
  bf16_t* k_ws  = (bf16_t*)(ws + 24 * MB);   // frag-linear per (b,h)
  bf16_t* vt_ws = (bf16_t*)(ws + 32 * MB);   // frag-linear per (b,h)
  bf16_t* at_ws = (bf16_t*)(ws + 40 * MB);

  hipLaunchKernelGGL(cast_all_k, dim3(8192), dim3(256), 0, stream,
                     x, wq, wk, wv, wo, xb, wqb, wkb, wvb, wob);

  hipLaunchKernelGGL(gemm_bt_k, dim3(32, 8, 3), dim3(512), 0, stream,
                     xb, wqb, wkb, wvb, q_ws, k_ws, vt_ws);

  hipLaunchKernelGGL(attn_fused_k, dim3(16, 32), dim3(512), 0, stream,
                     q_ws, k_ws, vt_ws, at_ws);

  hipLaunchKernelGGL(gemm_out_k, dim3(32, 16), dim3(512), 0, stream,
                     at_ws, wob, bo, out);
}